// Round 3
// baseline (521.160 us; speedup 1.0000x reference)
//
#include <hip/hip_runtime.h>
#include <hip/hip_bf16.h>
#include <math.h>

#define BDIM 2
#define NDIM 512
#define HID 768
#define BIAF 256
#define CLS 14
#define DD 257   // BIAF+1
#define NPOS 30
#define SDIM 25
#define HSZ 539  // 2*257+25
#define PK 288   // padded contraction length (i and j), 9*32
#define PJ 384   // packWT j-rows padding (3*128)

typedef unsigned short ushort_t;
typedef __attribute__((ext_vector_type(8))) short short8;   // 8 bf16
typedef __attribute__((ext_vector_type(4))) float floatx4;  // 4 f32

#define MFMA16(a, b, c) __builtin_amdgcn_mfma_f32_16x16x32_bf16((a), (b), (c), 0, 0, 0)

__device__ inline float bf2f(ushort_t u) {
    union { unsigned int i; float f; } c; c.i = ((unsigned)u) << 16; return c.f;
}
__device__ inline ushort_t f2bf(float f) {
    __hip_bfloat16 h = __float2bfloat16(f);
    return *(ushort_t*)&h;
}

template<typename T> __device__ inline float ldT(const T* p);
template<> __device__ inline float ldT<float>(const float* p) { return *p; }
template<> __device__ inline float ldT<ushort_t>(const ushort_t* p) { return bf2f(*p); }

// ---------------------------------------------------------------------------
// detect: flag=1 -> buffers are bf16 ; flag=0 -> f32
// ---------------------------------------------------------------------------
__global__ void detect_dtype(const ushort_t* __restrict__ x, int* __restrict__ flag) {
    __shared__ float red[256];
    float mx = 0.f;
    for (int i = threadIdx.x; i < 8192; i += 256) {
        float v = bf2f(x[i]);
        if (v != v) v = 1e30f;
        mx = fmaxf(mx, fabsf(v));
    }
    red[threadIdx.x] = mx;
    __syncthreads();
    for (int s = 128; s > 0; s >>= 1) {
        if (threadIdx.x < s) red[threadIdx.x] = fmaxf(red[threadIdx.x], red[threadIdx.x + s]);
        __syncthreads();
    }
    if (threadIdx.x == 0) *flag = (red[0] < 1000.0f) ? 1 : 0;
}

// ===========================================================================
// bf16 / MFMA path
// ===========================================================================

// fill pad columns of h1b/t1b: col 256 = 1.0, cols 257..287 = 0
__global__ void fill_pads(const int* __restrict__ flag,
                          ushort_t* __restrict__ h1b, ushort_t* __restrict__ t1b) {
    if (*flag == 0) return;
    int idx = blockIdx.x * 256 + threadIdx.x;          // 65536 items
    int buf = idx >> 15;
    int tok = (idx >> 5) & 1023;
    int c   = 256 + (idx & 31);
    ushort_t val = (c == 256) ? (ushort_t)0x3F80 : (ushort_t)0;
    (buf ? t1b : h1b)[(size_t)tok * PK + c] = val;
}

// packWT[k][j in 0..PJ][i in 0..PK] = biafW[k][i][j] (zero-padded)
__global__ void repack_WT(const int* __restrict__ flag,
                          const ushort_t* __restrict__ biafW,
                          ushort_t* __restrict__ packWT) {
    if (*flag == 0) return;
    int idx = blockIdx.x * 256 + threadIdx.x;          // 14*384*288 = 1548288
    int k = idx / (PJ * PK);
    int rem = idx % (PJ * PK);
    int j = rem / PK;
    int i = rem % PK;
    ushort_t v = (i < DD && j < DD) ? biafW[((size_t)k * DD + i) * DD + j] : (ushort_t)0;
    packWT[idx] = v;
}

// proj_mfma: 4 projections as GEMMs, direct-global MFMA frags, no LDS.
// grid 256 blocks x 256 thr; bx: proj = bx>>6, mt = (bx>>2)&15, ft = bx&3
__global__ __launch_bounds__(256) void proj_mfma(
    const ushort_t* __restrict__ x, const ushort_t* __restrict__ y,
    const ushort_t* __restrict__ m1w, const ushort_t* __restrict__ m1b,
    const ushort_t* __restrict__ m2w, const ushort_t* __restrict__ m2b,
    const ushort_t* __restrict__ hw,  const ushort_t* __restrict__ hb,
    const ushort_t* __restrict__ tw,  const ushort_t* __restrict__ tb,
    const int* __restrict__ flag,
    ushort_t* __restrict__ h1b, ushort_t* __restrict__ t1b,
    float* __restrict__ headf, float* __restrict__ tailf)
{
    if (*flag == 0) return;
    const int bx = blockIdx.x;
    const int proj = bx >> 6;
    const int mt = (bx >> 2) & 15;
    const int ft = bx & 3;
    const int wave = threadIdx.x >> 6, L = threadIdx.x & 63;
    const int quad = L >> 4, l16 = L & 15;
    const int m0w = mt * 64 + wave * 16;   // this wave's 16 token rows
    const int f0 = ft * 64;                // 64 features via 4 n-frags

    const ushort_t* src  = (proj == 1) ? y : x;
    const ushort_t* wmat = (proj == 0) ? m1w : (proj == 1) ? m2w : (proj == 2) ? hw : tw;
    const ushort_t* bias = (proj == 0) ? m1b : (proj == 1) ? m2b : (proj == 2) ? hb : tb;

    const ushort_t* arow = src + (size_t)(m0w + l16) * HID + quad * 8;
    const ushort_t* br0 = wmat + (size_t)(f0 + l16) * HID + quad * 8;

    floatx4 acc[4];
    #pragma unroll
    for (int nf = 0; nf < 4; ++nf)
        #pragma unroll
        for (int r = 0; r < 4; ++r) acc[nf][r] = 0.f;

    for (int k0 = 0; k0 < HID; k0 += 32) {
        short8 a = *(const short8*)(arow + k0);
        #pragma unroll
        for (int nf = 0; nf < 4; ++nf) {
            short8 b = *(const short8*)(br0 + (size_t)nf * 16 * HID + k0);
            acc[nf] = MFMA16(a, b, acc[nf]);
        }
    }

    #pragma unroll
    for (int nf = 0; nf < 4; ++nf) {
        int feat = f0 + nf * 16 + l16;
        float bv = bf2f(bias[feat]);
        #pragma unroll
        for (int r = 0; r < 4; ++r) {
            int tok = m0w + quad * 4 + r;
            float v = acc[nf][r] + bv;
            if (proj == 0) {
                float g = 0.5f * v * (1.0f + erff(v * 0.70710678118654752f));
                h1b[(size_t)tok * PK + feat] = f2bf(g);
            } else if (proj == 1) {
                float g = 0.5f * v * (1.0f + erff(v * 0.70710678118654752f));
                t1b[(size_t)tok * PK + feat] = f2bf(g);
            } else if (proj == 2) {
                headf[(size_t)tok * 256 + feat] = (v >= 0.f) ? v : 0.01f * v;
            } else {
                tailf[(size_t)tok * 256 + feat] = (v >= 0.f) ? v : 0.01f * v;
            }
        }
    }
}

// hk[b][k][m] = sum_f headf[tok][f]*Wh[k][f] + Wh[k][256]; same for tk with Wt
__global__ __launch_bounds__(256) void hk_tk_kernel(
    const int* __restrict__ flag,
    const float* __restrict__ headf, const float* __restrict__ tailf,
    const ushort_t* __restrict__ W,
    float* __restrict__ hk, float* __restrict__ tk)
{
    if (*flag == 0) return;
    int p = blockIdx.x * 256 + threadIdx.x;  // 32768 items
    int which = p >> 14;                     // 0=hk, 1=tk
    int idx = p & 16383;
    int tok = idx >> 4;
    int k = idx & 15;
    if (k >= CLS) return;
    const float* row = (which ? tailf : headf) + (size_t)tok * 256;
    const ushort_t* wr = W + (size_t)k * HSZ + (which ? DD : 0);
    float acc = 0.f;
    for (int f4 = 0; f4 < 64; ++f4) {
        float4 rv = *(const float4*)(row + f4 * 4);
        ushort4 wv = *(const ushort4*)(wr + f4 * 4);
        acc += rv.x * bf2f(wv.x) + rv.y * bf2f(wv.y) + rv.z * bf2f(wv.z) + rv.w * bf2f(wv.w);
    }
    acc += bf2f(wr[256]);
    float* dst = which ? tk : hk;
    dst[(size_t)(tok >> 9) * CLS * NDIM + (size_t)k * NDIM + (tok & 511)] = acc;
}

// mb_mfma: A[bk][m][j] = sum_i h1b[b][m][i] * biafW[k][i][j], j padded to 288
// grid (3 jt, 4 mt, 28 bk), block 4 waves, wave tile 64x64
__global__ __launch_bounds__(256) void mb_mfma(
    const int* __restrict__ flag,
    const ushort_t* __restrict__ h1b, const ushort_t* __restrict__ packWT,
    ushort_t* __restrict__ Ab)
{
    if (*flag == 0) return;
    const int jt = blockIdx.x, mt = blockIdx.y, bk = blockIdx.z;
    const int b = bk / CLS, k = bk % CLS;
    const int wave = threadIdx.x >> 6, L = threadIdx.x & 63;
    const int quad = L >> 4, l16 = L & 15;
    const int m0 = mt * 128 + (wave >> 1) * 64;
    const int j0 = jt * 128 + (wave & 1) * 64;
    const ushort_t* A = h1b + (size_t)b * NDIM * PK;
    const ushort_t* BT = packWT + (size_t)k * PJ * PK;

    const ushort_t* ar[4]; const ushort_t* br[4];
    #pragma unroll
    for (int i = 0; i < 4; ++i) ar[i] = A + (size_t)(m0 + i * 16 + l16) * PK + quad * 8;
    #pragma unroll
    for (int i = 0; i < 4; ++i) br[i] = BT + (size_t)(j0 + i * 16 + l16) * PK + quad * 8;

    floatx4 acc[4][4];
    #pragma unroll
    for (int mi = 0; mi < 4; ++mi)
        #pragma unroll
        for (int ni = 0; ni < 4; ++ni)
            #pragma unroll
            for (int r = 0; r < 4; ++r) acc[mi][ni][r] = 0.f;

    for (int k0 = 0; k0 < PK; k0 += 32) {
        short8 a[4], bb[4];
        #pragma unroll
        for (int i = 0; i < 4; ++i) a[i] = *(const short8*)(ar[i] + k0);
        #pragma unroll
        for (int i = 0; i < 4; ++i) bb[i] = *(const short8*)(br[i] + k0);
        #pragma unroll
        for (int mi = 0; mi < 4; ++mi)
            #pragma unroll
            for (int ni = 0; ni < 4; ++ni)
                acc[mi][ni] = MFMA16(a[mi], bb[ni], acc[mi][ni]);
    }

    ushort_t* Aout = Ab + (size_t)bk * NDIM * PK;
    #pragma unroll
    for (int mi = 0; mi < 4; ++mi) {
        #pragma unroll
        for (int r = 0; r < 4; ++r) {
            int row = m0 + mi * 16 + quad * 4 + r;
            #pragma unroll
            for (int ni = 0; ni < 4; ++ni) {
                int col = j0 + ni * 16 + l16;
                if (col < PK) Aout[(size_t)row * PK + col] = f2bf(acc[mi][ni][r]);
            }
        }
    }
}

// mo_mfma: out[bk][m][n] = sum_j Ab[bk][m][j]*t1b[b][n][j] + hk + tk + sk
// grid (4 nt, 4 mt, 28 bk)
__global__ __launch_bounds__(256) void mo_mfma(
    const int* __restrict__ flag,
    const ushort_t* __restrict__ Ab, const ushort_t* __restrict__ t1b,
    const float* __restrict__ hk, const float* __restrict__ tk,
    const float* __restrict__ sk,
    ushort_t* __restrict__ out)
{
    if (*flag == 0) return;
    __shared__ float skr[NPOS];
    const int nt = blockIdx.x, mt = blockIdx.y, bk = blockIdx.z;
    const int b = bk / CLS, k = bk % CLS;
    if (threadIdx.x < NPOS) skr[threadIdx.x] = sk[k * NPOS + threadIdx.x];
    __syncthreads();
    const int wave = threadIdx.x >> 6, L = threadIdx.x & 63;
    const int quad = L >> 4, l16 = L & 15;
    const int m0 = mt * 128 + (wave >> 1) * 64;
    const int n0 = nt * 128 + (wave & 1) * 64;
    const ushort_t* A = Ab + (size_t)bk * NDIM * PK;
    const ushort_t* BT = t1b + (size_t)b * NDIM * PK;

    const ushort_t* ar[4]; const ushort_t* br[4];
    #pragma unroll
    for (int i = 0; i < 4; ++i) ar[i] = A + (size_t)(m0 + i * 16 + l16) * PK + quad * 8;
    #pragma unroll
    for (int i = 0; i < 4; ++i) br[i] = BT + (size_t)(n0 + i * 16 + l16) * PK + quad * 8;

    floatx4 acc[4][4];
    #pragma unroll
    for (int mi = 0; mi < 4; ++mi)
        #pragma unroll
        for (int ni = 0; ni < 4; ++ni)
            #pragma unroll
            for (int r = 0; r < 4; ++r) acc[mi][ni][r] = 0.f;

    for (int k0 = 0; k0 < PK; k0 += 32) {
        short8 a[4], bb[4];
        #pragma unroll
        for (int i = 0; i < 4; ++i) a[i] = *(const short8*)(ar[i] + k0);
        #pragma unroll
        for (int i = 0; i < 4; ++i) bb[i] = *(const short8*)(br[i] + k0);
        #pragma unroll
        for (int mi = 0; mi < 4; ++mi)
            #pragma unroll
            for (int ni = 0; ni < 4; ++ni)
                acc[mi][ni] = MFMA16(a[mi], bb[ni], acc[mi][ni]);
    }

    const size_t obase = (size_t)bk * NDIM;
    #pragma unroll
    for (int mi = 0; mi < 4; ++mi) {
        #pragma unroll
        for (int r = 0; r < 4; ++r) {
            int row = m0 + mi * 16 + quad * 4 + r;
            float hv = hk[obase + row];
            #pragma unroll
            for (int ni = 0; ni < 4; ++ni) {
                int col = n0 + ni * 16 + l16;
                int d = col - row; d = d < -15 ? -15 : (d > 14 ? 14 : d); d += 15;
                float v = acc[mi][ni][r] + hv + tk[obase + col] + skr[d];
                out[(obase + row) * NDIM + col] = f2bf(v);
            }
        }
    }
}

// ===========================================================================
// f32 fallback path (old VALU kernels, guarded)
// ===========================================================================
__global__ __launch_bounds__(256) void stage1_f32(
    const float* __restrict__ x, const float* __restrict__ y,
    const float* __restrict__ m1w, const float* __restrict__ m1b,
    const float* __restrict__ m2w, const float* __restrict__ m2b,
    const float* __restrict__ hw,  const float* __restrict__ hb,
    const float* __restrict__ tw,  const float* __restrict__ tb,
    const float* __restrict__ W, const int* __restrict__ flag,
    float* __restrict__ h1, float* __restrict__ tT,
    float* __restrict__ hk, float* __restrict__ tk)
{
    if (*flag) return;
    __shared__ float xs[4][HID];
    __shared__ float ys[4][HID];
    __shared__ float hdv[4][BIAF];
    __shared__ float tlv[4][BIAF];
    const int tid = threadIdx.x;
    const int b  = blockIdx.x / (NDIM/4);
    const int m0 = (blockIdx.x % (NDIM/4)) * 4;

    for (int t = tid; t < 4*HID; t += 256) {
        int mm = t / HID, r = t % HID;
        xs[mm][r] = x[(size_t)(b*NDIM + m0+mm)*HID + r];
        ys[mm][r] = y[(size_t)(b*NDIM + m0+mm)*HID + r];
    }
    __syncthreads();

    const int i = tid;
    float ha[4] = {0,0,0,0}, ta[4] = {0,0,0,0}, da[4] = {0,0,0,0}, la[4] = {0,0,0,0};
    for (int r4 = 0; r4 < HID/4; ++r4) {
        float4 f1 = ((const float4*)(m1w + (size_t)i*HID))[r4];
        float4 f2 = ((const float4*)(m2w + (size_t)i*HID))[r4];
        float4 f3 = ((const float4*)(hw  + (size_t)i*HID))[r4];
        float4 f4v= ((const float4*)(tw  + (size_t)i*HID))[r4];
        #pragma unroll
        for (int mm = 0; mm < 4; ++mm) {
            float4 xv = *(const float4*)&xs[mm][r4*4];
            float4 yv = *(const float4*)&ys[mm][r4*4];
            ha[mm] += xv.x*f1.x + xv.y*f1.y + xv.z*f1.z + xv.w*f1.w;
            ta[mm] += yv.x*f2.x + yv.y*f2.y + yv.z*f2.z + yv.w*f2.w;
            da[mm] += xv.x*f3.x + xv.y*f3.y + xv.z*f3.z + xv.w*f3.w;
            la[mm] += xv.x*f4v.x + xv.y*f4v.y + xv.z*f4v.z + xv.w*f4v.w;
        }
    }
    #pragma unroll
    for (int mm = 0; mm < 4; ++mm) {
        float v = ha[mm] + m1b[i];
        h1[(size_t)(b*NDIM + m0+mm)*DD + i] = 0.5f*v*(1.0f + erff(v*0.70710678118654752f));
        float u = ta[mm] + m2b[i];
        tT[(size_t)(b*DD + i)*NDIM + (m0+mm)] = 0.5f*u*(1.0f + erff(u*0.70710678118654752f));
        float hv = da[mm] + hb[i]; hdv[mm][i] = hv >= 0.f ? hv : 0.01f*hv;
        float tv = la[mm] + tb[i]; tlv[mm][i] = tv >= 0.f ? tv : 0.01f*tv;
    }
    if (tid < 4) {
        h1[(size_t)(b*NDIM + m0+tid)*DD + BIAF] = 1.0f;
        tT[(size_t)(b*DD + BIAF)*NDIM + (m0+tid)] = 1.0f;
    }
    __syncthreads();
    if (tid < 4*CLS) {
        int mm = tid / CLS, k = tid % CLS;
        float acc = 0.f;
        for (int ii = 0; ii < BIAF; ++ii) acc += hdv[mm][ii] * W[k*HSZ + ii];
        acc += W[k*HSZ + BIAF];
        hk[(size_t)(b*CLS + k)*NDIM + (m0+mm)] = acc;
    } else if (tid >= 64 && tid < 64 + 4*CLS) {
        int t2 = tid - 64; int mm = t2 / CLS, k = t2 % CLS;
        float acc = 0.f;
        for (int ii = 0; ii < BIAF; ++ii) acc += tlv[mm][ii] * W[k*HSZ + DD + ii];
        acc += W[k*HSZ + DD + BIAF];
        tk[(size_t)(b*CLS + k)*NDIM + (m0+mm)] = acc;
    }
}

template<typename T>
__device__ void sk_body(const T* __restrict__ semb, const T* __restrict__ W,
                        float* __restrict__ sk)
{
    int idx = blockIdx.x * 256 + threadIdx.x;
    if (idx < CLS * NPOS) {
        int k = idx / NPOS, d = idx % NPOS;
        float acc = 0.f;
        for (int h = 0; h < SDIM; ++h)
            acc += ldT(semb + d*SDIM + h) * ldT(W + k*HSZ + 2*DD + h);
        sk[idx] = acc;
    }
}

__global__ void sk_kernel(const void* semb, const void* W,
                          const int* __restrict__ flag, float* __restrict__ sk)
{
    if (*flag) sk_body<ushort_t>((const ushort_t*)semb, (const ushort_t*)W, sk);
    else       sk_body<float>((const float*)semb, (const float*)W, sk);
}

__global__ __launch_bounds__(256) void gemm_biaf_f32(
    const float* __restrict__ h1, const float* __restrict__ biafW,
    const int* __restrict__ flag, float* __restrict__ A)
{
    if (*flag) return;
    __shared__ float Ls[32][36];
    __shared__ float Rs[32][128];
    const int tid = threadIdx.x;
    const int tx = tid % 32, ty = tid / 32;
    const int j0 = blockIdx.x * 128;
    const int m0 = blockIdx.y * 32;
    const int bk = blockIdx.z, b = bk / CLS, k = bk % CLS;
    const float* L = h1 + (size_t)(b*NDIM + m0) * DD;
    const float* R = biafW + (size_t)k * DD * DD;
    float acc[4][4] = {};
    for (int k0 = 0; k0 < DD; k0 += 32) {
        for (int t = tid; t < 32*32; t += 256) {
            int mm = t / 32, kk = t % 32;
            Ls[kk][mm] = (k0 + kk < DD) ? L[(size_t)mm*DD + k0 + kk] : 0.f;
        }
        for (int t = tid; t < 32*128; t += 256) {
            int kk = t / 128, c = t % 128;
            int kg = k0 + kk, jg = j0 + c;
            Rs[kk][c] = (kg < DD && jg < DD) ? R[(size_t)kg*DD + jg] : 0.f;
        }
        __syncthreads();
        #pragma unroll 8
        for (int kk = 0; kk < 32; ++kk) {
            float4 a  = *(const float4*)&Ls[kk][ty*4];
            float4 bb = *(const float4*)&Rs[kk][tx*4];
            float av[4] = {a.x, a.y, a.z, a.w};
            float bv[4] = {bb.x, bb.y, bb.z, bb.w};
            #pragma unroll
            for (int im = 0; im < 4; ++im)
                #pragma unroll
                for (int jn = 0; jn < 4; ++jn)
                    acc[im][jn] += av[im] * bv[jn];
        }
        __syncthreads();
    }
    float* Ab2 = A + ((size_t)(b*CLS + k)*NDIM) * DD;
    #pragma unroll
    for (int im = 0; im < 4; ++im) {
        int m = m0 + ty*4 + im;
        #pragma unroll
        for (int jn = 0; jn < 4; ++jn) {
            int j = j0 + tx*4 + jn;
            if (j < DD) Ab2[(size_t)m*DD + j] = acc[im][jn];
        }
    }
}

__global__ __launch_bounds__(256) void gemm_out_f32(
    const float* __restrict__ A, const float* __restrict__ tT,
    const float* __restrict__ hk, const float* __restrict__ tk,
    const float* __restrict__ sk, const int* __restrict__ flag,
    float* __restrict__ out)
{
    if (*flag) return;
    __shared__ float Ls[32][36];
    __shared__ float Rs[32][128];
    __shared__ float skr[NPOS];
    const int tid = threadIdx.x;
    const int tx = tid % 32, ty = tid / 32;
    const int n0 = blockIdx.x * 128;
    const int m0 = blockIdx.y * 32;
    const int bk = blockIdx.z, b = bk / CLS, k = bk % CLS;
    if (tid < NPOS) skr[tid] = sk[k*NPOS + tid];
    const float* L = A + ((size_t)(b*CLS + k)*NDIM + m0) * DD;
    const float* R = tT + (size_t)b * DD * NDIM + n0;
    float acc[4][4] = {};
    for (int k0 = 0; k0 < DD; k0 += 32) {
        for (int t = tid; t < 32*32; t += 256) {
            int mm = t / 32, kk = t % 32;
            Ls[kk][mm] = (k0 + kk < DD) ? L[(size_t)mm*DD + k0 + kk] : 0.f;
        }
        for (int t = tid; t < 32*128; t += 256) {
            int kk = t / 128, c = t % 128;
            Rs[kk][c] = (k0 + kk < DD) ? R[(size_t)(k0+kk)*NDIM + c] : 0.f;
        }
        __syncthreads();
        #pragma unroll 8
        for (int kk = 0; kk < 32; ++kk) {
            float4 a  = *(const float4*)&Ls[kk][ty*4];
            float4 bb = *(const float4*)&Rs[kk][tx*4];
            float av[4] = {a.x, a.y, a.z, a.w};
            float bv[4] = {bb.x, bb.y, bb.z, bb.w};
            #pragma unroll
            for (int im = 0; im < 4; ++im)
                #pragma unroll
                for (int jn = 0; jn < 4; ++jn)
                    acc[im][jn] += av[im] * bv[jn];
        }
        __syncthreads();
    }
    const int base = (b*CLS + k)*NDIM;
    float hkv[4], tkv[4];
    #pragma unroll
    for (int im = 0; im < 4; ++im) hkv[im] = hk[(size_t)base + m0 + ty*4 + im];
    #pragma unroll
    for (int jn = 0; jn < 4; ++jn) tkv[jn] = tk[(size_t)base + n0 + tx*4 + jn];
    #pragma unroll
    for (int im = 0; im < 4; ++im) {
        int m = m0 + ty*4 + im;
        float vals[4];
        #pragma unroll
        for (int jn = 0; jn < 4; ++jn) {
            int n = n0 + tx*4 + jn;
            int d = n - m; d = d < -15 ? -15 : (d > 14 ? 14 : d); d += 15;
            vals[jn] = acc[im][jn] + hkv[im] + tkv[jn] + skr[d];
        }
        *(float4*)&out[((size_t)base + m)*NDIM + n0 + tx*4] =
            make_float4(vals[0], vals[1], vals[2], vals[3]);
    }
}

// ---------------------------------------------------------------------------
extern "C" void kernel_launch(void* const* d_in, const int* in_sizes, int n_in,
                              void* d_out, int out_size, void* d_ws, size_t ws_size,
                              hipStream_t stream) {
    const void* x    = d_in[0];
    const void* y    = d_in[1];
    // d_in[2] = z : unused
    const void* m1w  = d_in[3];
    const void* m1b  = d_in[4];
    const void* m2w  = d_in[5];
    const void* m2b  = d_in[6];
    const void* hw   = d_in[7];
    const void* hb   = d_in[8];
    const void* tw   = d_in[9];
    const void* tb   = d_in[10];
    const void* biafW= d_in[11];
    const void* W    = d_in[12];
    const void* semb = d_in[13];

    char* base = (char*)d_ws;
    int* flag = (int*)base;
    char* p = base + 256;
    float* hk  = (float*)p;                    // 57344 B
    float* tk  = (float*)(p + 57344);          // 57344 B
    float* skp = (float*)(p + 114688);         // 2048 B
    char* q = p + 116736;
    // bf16-path buffers
    ushort_t* h1b    = (ushort_t*)q;                                  // 589824
    ushort_t* t1b    = (ushort_t*)(q + 589824);                       // 589824
    ushort_t* packWT = (ushort_t*)(q + 2*589824);                     // 3096576
    ushort_t* Abuf   = (ushort_t*)(q + 2*589824 + 3096576);           // 8257536
    float*    headf  = (float*)(q + 2*589824 + 3096576 + 8257536);    // 1048576
    float*    tailf  = (float*)(q + 2*589824 + 3096576 + 8257536 + 1048576);
    // f32-path buffers (alias same region; only one path runs)
    float* h1f = (float*)q;
    float* tTf = h1f + (size_t)BDIM*NDIM*DD;
    float* Af  = tTf + (size_t)BDIM*DD*NDIM;

    detect_dtype<<<1, 256, 0, stream>>>((const ushort_t*)x, flag);

    // bf16 path
    fill_pads<<<256, 256, 0, stream>>>(flag, h1b, t1b);
    repack_WT<<<6048, 256, 0, stream>>>(flag, (const ushort_t*)biafW, packWT);
    proj_mfma<<<256, 256, 0, stream>>>(
        (const ushort_t*)x, (const ushort_t*)y,
        (const ushort_t*)m1w, (const ushort_t*)m1b,
        (const ushort_t*)m2w, (const ushort_t*)m2b,
        (const ushort_t*)hw, (const ushort_t*)hb,
        (const ushort_t*)tw, (const ushort_t*)tb,
        flag, h1b, t1b, headf, tailf);
    hk_tk_kernel<<<128, 256, 0, stream>>>(flag, headf, tailf, (const ushort_t*)W, hk, tk);

    // f32 path
    stage1_f32<<<BDIM*(NDIM/4), 256, 0, stream>>>(
        (const float*)x, (const float*)y,
        (const float*)m1w, (const float*)m1b, (const float*)m2w, (const float*)m2b,
        (const float*)hw, (const float*)hb, (const float*)tw, (const float*)tb,
        (const float*)W, flag, h1f, tTf, hk, tk);

    // shared
    sk_kernel<<<2, 256, 0, stream>>>(semb, W, flag, skp);

    // bf16 path GEMMs
    mb_mfma<<<dim3(3, 4, BDIM*CLS), 256, 0, stream>>>(flag, h1b, packWT, Abuf);
    // f32 path GEMMs
    gemm_biaf_f32<<<dim3(3, NDIM/32, BDIM*CLS), 256, 0, stream>>>(
        h1f, (const float*)biafW, flag, Af);

    mo_mfma<<<dim3(4, 4, BDIM*CLS), 256, 0, stream>>>(
        flag, Abuf, t1b, hk, tk, skp, (ushort_t*)d_out);
    gemm_out_f32<<<dim3(4, NDIM/32, BDIM*CLS), 256, 0, stream>>>(
        Af, tTf, hk, tk, skp, flag, (float*)d_out);
}

// Round 4
// 217.056 us; speedup vs baseline: 2.4010x; 2.4010x over previous
//
#include <hip/hip_runtime.h>
#include <hip/hip_bf16.h>
#include <math.h>

#define BDIM 2
#define NDIM 512
#define HID 768
#define BIAF 256
#define CLS 14
#define DD 257   // BIAF+1
#define NPOS 30
#define SDIM 25
#define HSZ 539  // 2*257+25
#define PK 288   // padded contraction length (i and j), 9*32
#define PJ 384   // packW j-rows padding

typedef unsigned short ushort_t;
typedef __attribute__((ext_vector_type(8))) short short8;   // 8 bf16
typedef __attribute__((ext_vector_type(4))) float floatx4;  // 4 f32

#define MFMA16(a, b, c) __builtin_amdgcn_mfma_f32_16x16x32_bf16((a), (b), (c), 0, 0, 0)

__device__ inline float bf2f(ushort_t u) {
    union { unsigned int i; float f; } c; c.i = ((unsigned)u) << 16; return c.f;
}
__device__ inline ushort_t f2bf(float f) {
    __hip_bfloat16 h = __float2bfloat16(f);
    return *(ushort_t*)&h;
}

// split 8 f32 into hi/lo bf16 frags
__device__ inline void split8(const float* v, short8& hi, short8& lo) {
    #pragma unroll
    for (int j = 0; j < 8; ++j) {
        ushort_t h = f2bf(v[j]);
        float hf = bf2f(h);
        ((short*)&hi)[j] = (short)h;
        ((short*)&lo)[j] = (short)f2bf(v[j] - hf);
    }
}

// ---------------------------------------------------------------------------
// repack_t: packW[k][j][i] = bf16(biafW[k][i][j]), zero-padded to PJ x PK
// 32x32 LDS transpose tiles. grid (9 it, 12 jt, 14 k), 256 thr
// ---------------------------------------------------------------------------
__global__ __launch_bounds__(256) void repack_t(
    const float* __restrict__ biafW, ushort_t* __restrict__ packW)
{
    __shared__ float tile[32][33];
    const int i0 = blockIdx.x * 32;
    const int j0 = blockIdx.y * 32;
    const int k  = blockIdx.z;
    const int r8 = threadIdx.x >> 5;   // 0..7
    const int c  = threadIdx.x & 31;
    #pragma unroll
    for (int rr = 0; rr < 4; ++rr) {
        int r = rr * 8 + r8;
        int gi = i0 + r, gj = j0 + c;
        tile[r][c] = (gi < DD && gj < DD) ? biafW[((size_t)k * DD + gi) * DD + gj] : 0.f;
    }
    __syncthreads();
    #pragma unroll
    for (int rr = 0; rr < 4; ++rr) {
        int jr = rr * 8 + r8;
        packW[((size_t)k * PJ + (j0 + jr)) * PK + i0 + c] = f2bf(tile[c][jr]);
    }
}

// ---------------------------------------------------------------------------
// fill pad columns of h1/t1 hi/lo planes: col 256 = 1.0(hi)/0(lo), 257..287 = 0
// ---------------------------------------------------------------------------
__global__ void fill_pads(ushort_t* __restrict__ h1hi, ushort_t* __restrict__ h1lo,
                          ushort_t* __restrict__ t1hi, ushort_t* __restrict__ t1lo) {
    int idx = blockIdx.x * 256 + threadIdx.x;          // 131072 items
    int plane = idx >> 15;                             // 0..3
    int tok = (idx >> 5) & 1023;
    int c   = 256 + (idx & 31);
    ushort_t* dst = (plane == 0) ? h1hi : (plane == 1) ? h1lo : (plane == 2) ? t1hi : t1lo;
    ushort_t val = (c == 256 && (plane == 0 || plane == 2)) ? (ushort_t)0x3F80 : (ushort_t)0;
    dst[(size_t)tok * PK + c] = val;
}

// ---------------------------------------------------------------------------
// proj_mfma: 4 projections (f32 in, split-bf16 MFMA, 3-term)
// grid 256: proj = bx>>6, mt = (bx>>2)&15, ft = bx&3
// ---------------------------------------------------------------------------
__global__ __launch_bounds__(256) void proj_mfma(
    const float* __restrict__ x, const float* __restrict__ y,
    const float* __restrict__ m1w, const float* __restrict__ m1b,
    const float* __restrict__ m2w, const float* __restrict__ m2b,
    const float* __restrict__ hw,  const float* __restrict__ hb,
    const float* __restrict__ tw,  const float* __restrict__ tb,
    ushort_t* __restrict__ h1hi, ushort_t* __restrict__ h1lo,
    ushort_t* __restrict__ t1hi, ushort_t* __restrict__ t1lo,
    float* __restrict__ headf, float* __restrict__ tailf)
{
    const int bx = blockIdx.x;
    const int proj = bx >> 6;
    const int mt = (bx >> 2) & 15;
    const int ft = bx & 3;
    const int wave = threadIdx.x >> 6, L = threadIdx.x & 63;
    const int quad = L >> 4, l16 = L & 15;
    const int m0w = mt * 64 + wave * 16;   // 16 token rows for this wave
    const int f0 = ft * 64;                // 64 features via 4 n-frags

    const float* src  = (proj == 1) ? y : x;
    const float* wmat = (proj == 0) ? m1w : (proj == 1) ? m2w : (proj == 2) ? hw : tw;
    const float* bias = (proj == 0) ? m1b : (proj == 1) ? m2b : (proj == 2) ? hb : tb;

    const float* arow = src + (size_t)(m0w + l16) * HID + quad * 8;

    floatx4 acc[4];
    #pragma unroll
    for (int nf = 0; nf < 4; ++nf)
        #pragma unroll
        for (int r = 0; r < 4; ++r) acc[nf][r] = 0.f;

    for (int k0 = 0; k0 < HID; k0 += 32) {
        float av[8];
        *(float4*)&av[0] = *(const float4*)(arow + k0);
        *(float4*)&av[4] = *(const float4*)(arow + k0 + 4);
        short8 ahi, alo;
        split8(av, ahi, alo);
        #pragma unroll
        for (int nf = 0; nf < 4; ++nf) {
            const float* brow = wmat + (size_t)(f0 + nf * 16 + l16) * HID + quad * 8 + k0;
            float bv[8];
            *(float4*)&bv[0] = *(const float4*)(brow);
            *(float4*)&bv[4] = *(const float4*)(brow + 4);
            short8 bhi, blo;
            split8(bv, bhi, blo);
            acc[nf] = MFMA16(ahi, bhi, acc[nf]);
            acc[nf] = MFMA16(alo, bhi, acc[nf]);
            acc[nf] = MFMA16(ahi, blo, acc[nf]);
        }
    }

    #pragma unroll
    for (int nf = 0; nf < 4; ++nf) {
        int feat = f0 + nf * 16 + l16;
        float bv = bias[feat];
        #pragma unroll
        for (int r = 0; r < 4; ++r) {
            int tok = m0w + quad * 4 + r;
            float v = acc[nf][r] + bv;
            if (proj == 0) {
                float g = 0.5f * v * (1.0f + erff(v * 0.70710678118654752f));
                ushort_t h = f2bf(g);
                h1hi[(size_t)tok * PK + feat] = h;
                h1lo[(size_t)tok * PK + feat] = f2bf(g - bf2f(h));
            } else if (proj == 1) {
                float g = 0.5f * v * (1.0f + erff(v * 0.70710678118654752f));
                ushort_t h = f2bf(g);
                t1hi[(size_t)tok * PK + feat] = h;
                t1lo[(size_t)tok * PK + feat] = f2bf(g - bf2f(h));
            } else if (proj == 2) {
                headf[(size_t)tok * 256 + feat] = (v >= 0.f) ? v : 0.01f * v;
            } else {
                tailf[(size_t)tok * 256 + feat] = (v >= 0.f) ? v : 0.01f * v;
            }
        }
    }
}

// ---------------------------------------------------------------------------
// hk[b][k][m] = dot(headf[tok], Wh[k]) + Wh[k][256]; tk likewise with Wt
// ---------------------------------------------------------------------------
__global__ __launch_bounds__(256) void hk_tk_kernel(
    const float* __restrict__ headf, const float* __restrict__ tailf,
    const float* __restrict__ W,
    float* __restrict__ hk, float* __restrict__ tk)
{
    int p = blockIdx.x * 256 + threadIdx.x;  // 32768 items
    int which = p >> 14;                     // 0=hk, 1=tk
    int idx = p & 16383;
    int tok = idx >> 4;
    int k = idx & 15;
    if (k >= CLS) return;
    const float* row = (which ? tailf : headf) + (size_t)tok * 256;
    const float* wr = W + (size_t)k * HSZ + (which ? DD : 0);
    float acc = 0.f;
    for (int f4 = 0; f4 < 64; ++f4) {
        float4 rv = *(const float4*)(row + f4 * 4);
        acc += rv.x * wr[f4*4] + rv.y * wr[f4*4+1] + rv.z * wr[f4*4+2] + rv.w * wr[f4*4+3];
    }
    acc += wr[256];
    float* dst = which ? tk : hk;
    dst[(size_t)(tok >> 9) * CLS * NDIM + (size_t)k * NDIM + (tok & 511)] = acc;
}

// ---------------------------------------------------------------------------
// sk[k][d] = sum_h size_emb[d][h] * Ws[k][h]
// ---------------------------------------------------------------------------
__global__ void sk_kernel(const float* __restrict__ semb, const float* __restrict__ W,
                          float* __restrict__ sk)
{
    int idx = blockIdx.x * 256 + threadIdx.x;
    if (idx < CLS * NPOS) {
        int k = idx / NPOS, d = idx % NPOS;
        float acc = 0.f;
        for (int h = 0; h < SDIM; ++h)
            acc += semb[d*SDIM + h] * W[k*HSZ + 2*DD + h];
        sk[idx] = acc;
    }
}

// ---------------------------------------------------------------------------
// mb_mfma: A[bk][m][j] = sum_i h1[b][m][i] * biafW[k][i][j]  (2-term split)
// grid (3 jt, 4 mt, 28 bk), wave tile 64x64; A stored bf16, j-pad zeros
// ---------------------------------------------------------------------------
__global__ __launch_bounds__(256) void mb_mfma(
    const ushort_t* __restrict__ h1hi, const ushort_t* __restrict__ h1lo,
    const ushort_t* __restrict__ packW,
    ushort_t* __restrict__ Ab)
{
    const int jt = blockIdx.x, mt = blockIdx.y, bk = blockIdx.z;
    const int b = bk / CLS, k = bk % CLS;
    const int wave = threadIdx.x >> 6, L = threadIdx.x & 63;
    const int quad = L >> 4, l16 = L & 15;
    const int m0 = mt * 128 + (wave >> 1) * 64;
    const int j0 = jt * 128 + (wave & 1) * 64;
    const size_t abase = (size_t)b * NDIM * PK;
    const ushort_t* BT = packW + (size_t)k * PJ * PK;

    size_t aoff[4]; size_t boff[4];
    #pragma unroll
    for (int i = 0; i < 4; ++i) aoff[i] = abase + (size_t)(m0 + i * 16 + l16) * PK + quad * 8;
    #pragma unroll
    for (int i = 0; i < 4; ++i) boff[i] = (size_t)(j0 + i * 16 + l16) * PK + quad * 8;

    floatx4 acc[4][4];
    #pragma unroll
    for (int mi = 0; mi < 4; ++mi)
        #pragma unroll
        for (int ni = 0; ni < 4; ++ni)
            #pragma unroll
            for (int r = 0; r < 4; ++r) acc[mi][ni][r] = 0.f;

    for (int k0 = 0; k0 < PK; k0 += 32) {
        short8 ahi[4], alo[4], bb[4];
        #pragma unroll
        for (int i = 0; i < 4; ++i) {
            ahi[i] = *(const short8*)(h1hi + aoff[i] + k0);
            alo[i] = *(const short8*)(h1lo + aoff[i] + k0);
            bb[i]  = *(const short8*)(BT + boff[i] + k0);
        }
        #pragma unroll
        for (int mi = 0; mi < 4; ++mi)
            #pragma unroll
            for (int ni = 0; ni < 4; ++ni) {
                acc[mi][ni] = MFMA16(ahi[mi], bb[ni], acc[mi][ni]);
                acc[mi][ni] = MFMA16(alo[mi], bb[ni], acc[mi][ni]);
            }
    }

    ushort_t* Aout = Ab + (size_t)bk * NDIM * PK;
    #pragma unroll
    for (int mi = 0; mi < 4; ++mi) {
        #pragma unroll
        for (int r = 0; r < 4; ++r) {
            int row = m0 + mi * 16 + quad * 4 + r;
            #pragma unroll
            for (int ni = 0; ni < 4; ++ni) {
                int col = j0 + ni * 16 + l16;
                if (col < PK) Aout[(size_t)row * PK + col] = f2bf(acc[mi][ni][r]);
            }
        }
    }
}

// ---------------------------------------------------------------------------
// mo_mfma: out[bk][m][n] = sum_j A[bk][m][j]*t1[b][n][j] + hk + tk + sk (2-term)
// grid (4 nt, 4 mt, 28 bk); f32 output
// ---------------------------------------------------------------------------
__global__ __launch_bounds__(256) void mo_mfma(
    const ushort_t* __restrict__ Ab,
    const ushort_t* __restrict__ t1hi, const ushort_t* __restrict__ t1lo,
    const float* __restrict__ hk, const float* __restrict__ tk,
    const float* __restrict__ sk,
    float* __restrict__ out)
{
    __shared__ float skr[NPOS];
    const int nt = blockIdx.x, mt = blockIdx.y, bk = blockIdx.z;
    const int b = bk / CLS, k = bk % CLS;
    if (threadIdx.x < NPOS) skr[threadIdx.x] = sk[k * NPOS + threadIdx.x];
    __syncthreads();
    const int wave = threadIdx.x >> 6, L = threadIdx.x & 63;
    const int quad = L >> 4, l16 = L & 15;
    const int m0 = mt * 128 + (wave >> 1) * 64;
    const int n0 = nt * 128 + (wave & 1) * 64;
    const ushort_t* A = Ab + (size_t)bk * NDIM * PK;
    const size_t tbase = (size_t)b * NDIM * PK;

    size_t aoff[4]; size_t boff[4];
    #pragma unroll
    for (int i = 0; i < 4; ++i) aoff[i] = (size_t)(m0 + i * 16 + l16) * PK + quad * 8;
    #pragma unroll
    for (int i = 0; i < 4; ++i) boff[i] = tbase + (size_t)(n0 + i * 16 + l16) * PK + quad * 8;

    floatx4 acc[4][4];
    #pragma unroll
    for (int mi = 0; mi < 4; ++mi)
        #pragma unroll
        for (int ni = 0; ni < 4; ++ni)
            #pragma unroll
            for (int r = 0; r < 4; ++r) acc[mi][ni][r] = 0.f;

    for (int k0 = 0; k0 < PK; k0 += 32) {
        short8 a[4], bhi[4], blo[4];
        #pragma unroll
        for (int i = 0; i < 4; ++i) {
            a[i]   = *(const short8*)(A + aoff[i] + k0);
            bhi[i] = *(const short8*)(t1hi + boff[i] + k0);
            blo[i] = *(const short8*)(t1lo + boff[i] + k0);
        }
        #pragma unroll
        for (int mi = 0; mi < 4; ++mi)
            #pragma unroll
            for (int ni = 0; ni < 4; ++ni) {
                acc[mi][ni] = MFMA16(a[mi], bhi[ni], acc[mi][ni]);
                acc[mi][ni] = MFMA16(a[mi], blo[ni], acc[mi][ni]);
            }
    }

    const size_t obase = (size_t)bk * NDIM;
    #pragma unroll
    for (int mi = 0; mi < 4; ++mi) {
        #pragma unroll
        for (int r = 0; r < 4; ++r) {
            int row = m0 + mi * 16 + quad * 4 + r;
            float hv = hk[obase + row];
            #pragma unroll
            for (int ni = 0; ni < 4; ++ni) {
                int col = n0 + ni * 16 + l16;
                int d = col - row; d = d < -15 ? -15 : (d > 14 ? 14 : d); d += 15;
                out[(obase + row) * NDIM + col] = acc[mi][ni][r] + hv + tk[obase + col] + skr[d];
            }
        }
    }
}

// ---------------------------------------------------------------------------
extern "C" void kernel_launch(void* const* d_in, const int* in_sizes, int n_in,
                              void* d_out, int out_size, void* d_ws, size_t ws_size,
                              hipStream_t stream) {
    const float* x    = (const float*)d_in[0];
    const float* y    = (const float*)d_in[1];
    // d_in[2] = z : unused
    const float* m1w  = (const float*)d_in[3];
    const float* m1b  = (const float*)d_in[4];
    const float* m2w  = (const float*)d_in[5];
    const float* m2b  = (const float*)d_in[6];
    const float* hw   = (const float*)d_in[7];
    const float* hb   = (const float*)d_in[8];
    const float* tw   = (const float*)d_in[9];
    const float* tb   = (const float*)d_in[10];
    const float* biafW= (const float*)d_in[11];
    const float* W    = (const float*)d_in[12];
    const float* semb = (const float*)d_in[13];

    char* p = (char*)d_ws;
    float* hk   = (float*)p;                    p += 57344;
    float* tk   = (float*)p;                    p += 57344;
    float* skp  = (float*)p;                    p += 2048;
    float* headf= (float*)p;                    p += 1048576;
    float* tailf= (float*)p;                    p += 1048576;
    ushort_t* h1hi = (ushort_t*)p;              p += 589824;
    ushort_t* h1lo = (ushort_t*)p;              p += 589824;
    ushort_t* t1hi = (ushort_t*)p;              p += 589824;
    ushort_t* t1lo = (ushort_t*)p;              p += 589824;
    ushort_t* packW= (ushort_t*)p;              p += 3096576;  // 14*384*288*2
    ushort_t* Abuf = (ushort_t*)p;              p += 8257536;  // 28*512*288*2

    repack_t<<<dim3(9, 12, CLS), 256, 0, stream>>>(biafW, packW);
    fill_pads<<<512, 256, 0, stream>>>(h1hi, h1lo, t1hi, t1lo);
    proj_mfma<<<256, 256, 0, stream>>>(x, y, m1w, m1b, m2w, m2b,
                                       hw, hb, tw, tb,
                                       h1hi, h1lo, t1hi, t1lo, headf, tailf);
    hk_tk_kernel<<<128, 256, 0, stream>>>(headf, tailf, W, hk, tk);
    sk_kernel<<<2, 256, 0, stream>>>(semb, W, skp);
    mb_mfma<<<dim3(3, 4, BDIM*CLS), 256, 0, stream>>>(h1hi, h1lo, packW, Abuf);
    mo_mfma<<<dim3(4, 4, BDIM*CLS), 256, 0, stream>>>(Abuf, t1hi, t1lo, hk, tk, skp,
                                                      (float*)d_out);
}